// Round 2
// baseline (4708.208 us; speedup 1.0000x reference)
//
#include <hip/hip_runtime.h>
#include <math.h>

typedef unsigned short u16;
typedef __attribute__((ext_vector_type(4))) float f4;

#define BB 32
#define TT 64
#define SS 128
#define DD 512
#define DS_ 1024
#define G4_ 2048

__device__ __forceinline__ float sigf(float x) { return 1.0f / (1.0f + expf(-x)); }

// ---------------------------------------------------------------------------
// mask dtype classifier: 0=u8(bool), 1=i32, 2=bf16, 3=f32. Deterministic.
// ---------------------------------------------------------------------------
__global__ void k_flag(const unsigned char* __restrict__ m, int* __restrict__ flag) {
    int tid = threadIdx.x;
    int badbyte = 0, nonz_off = 0, evenu16_nz = 0;
    for (int i = tid * 16; i < tid * 16 + 16; i++) {
        unsigned char c = m[i];
        if (c > 1) badbyte = 1;
        if ((i & 3) != 0 && c != 0) nonz_off = 1;
    }
    const u16* mu = (const u16*)m;
    for (int i = tid * 8; i < tid * 8 + 8; i++) {
        if ((i & 1) == 0 && mu[i] != 0) evenu16_nz = 1;
    }
    __shared__ int s_bad, s_noff, s_env;
    if (tid == 0) { s_bad = 0; s_noff = 0; s_env = 0; }
    __syncthreads();
    if (badbyte) atomicOr(&s_bad, 1);
    if (nonz_off) atomicOr(&s_noff, 1);
    if (evenu16_nz) atomicOr(&s_env, 1);
    __syncthreads();
    if (tid == 0) {
        int f;
        if (s_bad) f = s_env ? 2 : 3;   // float-looking bytes: bf16 vs f32
        else       f = s_noff ? 0 : 1;  // all {0,1} bytes: u8 vs i32
        *flag = f;
    }
}

// ---------------------------------------------------------------------------
// init: h0 = hiddens[0], h1 = hiddens[1] (f32 copy into double buffers)
// ---------------------------------------------------------------------------
__global__ void __launch_bounds__(256) k_init(const float* __restrict__ hid,
                                              float* __restrict__ h0, float* __restrict__ h1) {
    int i = blockIdx.x * 256 + threadIdx.x;   // 0 .. 32767
    float v = hid[i];
    if (i < BB * DD) h0[i] = v;
    else h1[i - BB * DD] = v;
}

// ---------------------------------------------------------------------------
// gih0[t][b][j] = b_ih0[j] + b_hh0[j] + sum_k embed[tok[b,t],k] * W_ih0[j,k]
// grid (64 dtiles, 64 t), 256 thr; thread = (b, dd); 4 gates per thread.
// ---------------------------------------------------------------------------
__global__ void __launch_bounds__(256) k_gih0(const int* __restrict__ tokens,
                                              const float* __restrict__ embed,
                                              const float* __restrict__ Wih,
                                              const float* __restrict__ bih,
                                              const float* __restrict__ bhh,
                                              float* __restrict__ gih0) {
    const int tid = threadIdx.x;
    const int d0 = blockIdx.x * 8;
    const int t = blockIdx.y;
    const int b = tid & 31, dd = tid >> 5;
    const int d = d0 + dd;
    __shared__ float xs[32 * 257];
    __shared__ int toks[32];
    if (tid < 32) toks[tid] = tokens[tid * TT + t];
    float acc[4];
#pragma unroll
    for (int g = 0; g < 4; g++) { int j = g * 512 + d; acc[g] = bih[j] + bhh[j]; }
    __syncthreads();
    for (int c = 0; c < 2; c++) {
        for (int idx = tid; idx < 32 * 64; idx += 256) {
            int b2 = idx >> 6, k4 = idx & 63;
            f4 v = *(const f4*)&embed[(size_t)toks[b2] * 512 + c * 256 + k4 * 4];
            float* dst = &xs[b2 * 257 + k4 * 4];
            dst[0] = v[0]; dst[1] = v[1]; dst[2] = v[2]; dst[3] = v[3];
        }
        __syncthreads();
        for (int k8 = 0; k8 < 32; k8++) {
            float w[4][8];
#pragma unroll
            for (int g = 0; g < 4; g++) {
                const f4* wp = (const f4*)&Wih[(size_t)(g * 512 + d) * 512 + c * 256 + k8 * 8];
                f4 wa = wp[0], wb = wp[1];
#pragma unroll
                for (int kk = 0; kk < 4; kk++) { w[g][kk] = wa[kk]; w[g][4 + kk] = wb[kk]; }
            }
#pragma unroll
            for (int kk = 0; kk < 8; kk++) {
                float xv = xs[b * 257 + k8 * 8 + kk];
#pragma unroll
                for (int g = 0; g < 4; g++) acc[g] += xv * w[g][kk];
            }
        }
        __syncthreads();
    }
    float* grow = gih0 + ((size_t)(t * 32 + b)) * 2048;
#pragma unroll
    for (int g = 0; g < 4; g++) grow[g * 512 + d] = acc[g];
}

// ---------------------------------------------------------------------------
// stepA: layer-0 LSTM cell for step t.
// gates = gih0[t] + h_prev @ W_hh0^T ; c2 -> h_next (carry bug), h2 -> h20
// ---------------------------------------------------------------------------
__global__ void __launch_bounds__(256) k_stepA(const float* __restrict__ gih0_t,
                                               const float* __restrict__ hp,
                                               const float* __restrict__ Whh0,
                                               const float* __restrict__ cells0,
                                               float* __restrict__ hn,
                                               float* __restrict__ h20) {
    const int tid = threadIdx.x;
    const int d0 = blockIdx.x * 8;
    const int b = tid & 31, dd = tid >> 5;
    const int d = d0 + dd;
    __shared__ float xs[32 * 257];
    float acc[4];
#pragma unroll
    for (int g = 0; g < 4; g++) acc[g] = gih0_t[(size_t)b * 2048 + g * 512 + d];
    for (int c = 0; c < 2; c++) {
        for (int idx = tid; idx < 32 * 64; idx += 256) {
            int b2 = idx >> 6, k4 = idx & 63;
            f4 v = *(const f4*)&hp[b2 * 512 + c * 256 + k4 * 4];
            float* dst = &xs[b2 * 257 + k4 * 4];
            dst[0] = v[0]; dst[1] = v[1]; dst[2] = v[2]; dst[3] = v[3];
        }
        __syncthreads();
        for (int k8 = 0; k8 < 32; k8++) {
            float w[4][8];
#pragma unroll
            for (int g = 0; g < 4; g++) {
                const f4* wp = (const f4*)&Whh0[(size_t)(g * 512 + d) * 512 + c * 256 + k8 * 8];
                f4 wa = wp[0], wb = wp[1];
#pragma unroll
                for (int kk = 0; kk < 4; kk++) { w[g][kk] = wa[kk]; w[g][4 + kk] = wb[kk]; }
            }
#pragma unroll
            for (int kk = 0; kk < 8; kk++) {
                float xv = xs[b * 257 + k8 * 8 + kk];
#pragma unroll
                for (int g = 0; g < 4; g++) acc[g] += xv * w[g][kk];
            }
        }
        __syncthreads();
    }
    float cell = cells0[b * 512 + d];
    float c2 = sigf(acc[1]) * cell + sigf(acc[0]) * tanhf(acc[2]);
    float h2 = sigf(acc[3]) * tanhf(c2);
    hn[b * 512 + d] = c2;      // faithful bug: carry gets the cell
    h20[b * 512 + d] = h2;
}

// ---------------------------------------------------------------------------
// stepB: layer-1 LSTM cell. gates = h20 @ W_ih1^T + h1p @ W_hh1^T + biases.
// writes h1_next (=c2) and H2[t] (=h2).
// ---------------------------------------------------------------------------
__global__ void __launch_bounds__(256) k_stepB(const float* __restrict__ h20,
                                               const float* __restrict__ h1p,
                                               const float* __restrict__ Wih1,
                                               const float* __restrict__ Whh1,
                                               const float* __restrict__ bih1,
                                               const float* __restrict__ bhh1,
                                               const float* __restrict__ cells1,
                                               float* __restrict__ h1n,
                                               float* __restrict__ H2t) {
    const int tid = threadIdx.x;
    const int d0 = blockIdx.x * 8;
    const int b = tid & 31, dd = tid >> 5;
    const int d = d0 + dd;
    __shared__ float xs[32 * 257];
    float acc[4];
#pragma unroll
    for (int g = 0; g < 4; g++) { int j = g * 512 + d; acc[g] = bih1[j] + bhh1[j]; }
    for (int c = 0; c < 4; c++) {
        const float* src = (c < 2) ? (h20 + c * 256) : (h1p + (c - 2) * 256);
        const float* W = (c < 2) ? Wih1 : Whh1;
        const int kw = (c & 1) * 256;
        for (int idx = tid; idx < 32 * 64; idx += 256) {
            int b2 = idx >> 6, k4 = idx & 63;
            f4 v = *(const f4*)&src[b2 * 512 + k4 * 4];
            float* dst = &xs[b2 * 257 + k4 * 4];
            dst[0] = v[0]; dst[1] = v[1]; dst[2] = v[2]; dst[3] = v[3];
        }
        __syncthreads();
        for (int k8 = 0; k8 < 32; k8++) {
            float w[4][8];
#pragma unroll
            for (int g = 0; g < 4; g++) {
                const f4* wp = (const f4*)&W[(size_t)(g * 512 + d) * 512 + kw + k8 * 8];
                f4 wa = wp[0], wb = wp[1];
#pragma unroll
                for (int kk = 0; kk < 4; kk++) { w[g][kk] = wa[kk]; w[g][4 + kk] = wb[kk]; }
            }
#pragma unroll
            for (int kk = 0; kk < 8; kk++) {
                float xv = xs[b * 257 + k8 * 8 + kk];
#pragma unroll
                for (int g = 0; g < 4; g++) acc[g] += xv * w[g][kk];
            }
        }
        __syncthreads();
    }
    float cell = cells1[b * 512 + d];
    float c2 = sigf(acc[1]) * cell + sigf(acc[0]) * tanhf(acc[2]);
    float h2 = sigf(acc[3]) * tanhf(c2);
    h1n[b * 512 + d] = c2;     // faithful bug
    H2t[b * 512 + d] = h2;
}

// ---------------------------------------------------------------------------
// XQ[t,b,:] = H2[t,b,:] @ W_in^T + b_in   (rows 2048, cols 1024, K 512)
// ---------------------------------------------------------------------------
__global__ void __launch_bounds__(256) k_x(const float* __restrict__ H2,
                                           const float* __restrict__ Win,
                                           const float* __restrict__ bin,
                                           float* __restrict__ XQ) {
    const int tid = threadIdx.x;
    const int j0 = blockIdx.x * 32;
    const int t = blockIdx.y;
    const int b = tid & 31, jj = tid >> 5;
    __shared__ float xs[32 * 257];
    float acc[4];
#pragma unroll
    for (int r = 0; r < 4; r++) acc[r] = bin[j0 + jj * 4 + r];
    const float* H2t = H2 + (size_t)t * 32 * 512;
    for (int c = 0; c < 2; c++) {
        for (int idx = tid; idx < 32 * 64; idx += 256) {
            int b2 = idx >> 6, k4 = idx & 63;
            f4 v = *(const f4*)&H2t[b2 * 512 + c * 256 + k4 * 4];
            float* dst = &xs[b2 * 257 + k4 * 4];
            dst[0] = v[0]; dst[1] = v[1]; dst[2] = v[2]; dst[3] = v[3];
        }
        __syncthreads();
        for (int k8 = 0; k8 < 32; k8++) {
            float w[4][8];
#pragma unroll
            for (int r = 0; r < 4; r++) {
                const f4* wp = (const f4*)&Win[(size_t)(j0 + jj * 4 + r) * 512 + c * 256 + k8 * 8];
                f4 wa = wp[0], wb = wp[1];
#pragma unroll
                for (int kk = 0; kk < 4; kk++) { w[r][kk] = wa[kk]; w[r][4 + kk] = wb[kk]; }
            }
#pragma unroll
            for (int kk = 0; kk < 8; kk++) {
                float xv = xs[b * 257 + k8 * 8 + kk];
#pragma unroll
                for (int r = 0; r < 4; r++) acc[r] += xv * w[r][kk];
            }
        }
        __syncthreads();
    }
    float* xrow = XQ + ((size_t)(t * 32 + b)) * 1024;
#pragma unroll
    for (int r = 0; r < 4; r++) xrow[j0 + jj * 4 + r] = acc[r];
}

// ---------------------------------------------------------------------------
// attention per (t,b): e = enc . xq, masked softmax, ctx = attn . enc
// ---------------------------------------------------------------------------
__global__ void __launch_bounds__(256) k_att(const float* __restrict__ XQ,
                                             const float* __restrict__ enc,
                                             const unsigned char* __restrict__ mask,
                                             const int* __restrict__ flag,
                                             float* __restrict__ CTX) {
    const int tid = threadIdx.x;
    const int b = blockIdx.x, t = blockIdx.y;
    __shared__ float xq[1024];
    __shared__ float ered[256];
    __shared__ float attn[128];
    __shared__ float red2[8];
    {
        f4 v = *(const f4*)&XQ[((size_t)(t * 32 + b)) * 1024 + tid * 4];
        float* dst = &xq[tid * 4];
        dst[0] = v[0]; dst[1] = v[1]; dst[2] = v[2]; dst[3] = v[3];
    }
    __syncthreads();
    const int s = tid >> 1, hh = tid & 1;
    float part = 0.f;
    const float* erow = enc + ((size_t)(b * 128 + s)) * 1024 + hh * 512;
    const float* xqh = &xq[hh * 512];
    for (int k4 = 0; k4 < 128; k4++) {
        f4 u = *(const f4*)&erow[k4 * 4];
#pragma unroll
        for (int kk = 0; kk < 4; kk++) part += u[kk] * xqh[k4 * 4 + kk];
    }
    ered[tid] = part;
    __syncthreads();
    float e = -INFINITY;
    if (tid < 128) {
        e = ered[2 * tid] + ered[2 * tid + 1];
        int f = *flag;
        bool msk;
        if (f == 0)      msk = mask[b * 128 + tid] != 0;
        else if (f == 1) msk = ((const int*)mask)[b * 128 + tid] != 0;
        else if (f == 2) msk = ((const u16*)mask)[b * 128 + tid] != 0;
        else             msk = ((const unsigned int*)mask)[b * 128 + tid] != 0;
        if (msk) e = -1e9f;
    }
    float v = e;
#pragma unroll
    for (int off = 32; off >= 1; off >>= 1) v = fmaxf(v, __shfl_xor(v, off));
    const int wave = tid >> 6;
    if ((tid & 63) == 0) red2[wave] = v;
    __syncthreads();
    float m = fmaxf(fmaxf(red2[0], red2[1]), fmaxf(red2[2], red2[3]));
    float p = (tid < 128) ? expf(e - m) : 0.f;
    float su = p;
#pragma unroll
    for (int off = 32; off >= 1; off >>= 1) su += __shfl_xor(su, off);
    __syncthreads();   // red2 reuse
    if ((tid & 63) == 0) red2[4 + wave] = su;
    __syncthreads();
    float S = (red2[4] + red2[5]) + (red2[6] + red2[7]);
    if (tid < 128) attn[tid] = p / S;
    __syncthreads();
    float c0 = 0, c1 = 0, c2 = 0, c3 = 0;
    const float* eb = enc + ((size_t)b * 128) * 1024 + tid * 4;
    for (int s2 = 0; s2 < 128; s2++) {
        float a = attn[s2];
        f4 u = *(const f4*)&eb[(size_t)s2 * 1024];
        c0 += a * u[0]; c1 += a * u[1]; c2 += a * u[2]; c3 += a * u[3];
    }
    float* crow = CTX + ((size_t)(t * 32 + b)) * 1024 + tid * 4;
    crow[0] = c0; crow[1] = c1; crow[2] = c2; crow[3] = c3;
}

// ---------------------------------------------------------------------------
// out[t,b,:] = tanh([ctx, s] @ W_out^T + b_out)  -> f32 d_out
// ---------------------------------------------------------------------------
__global__ void __launch_bounds__(256) k_out(const float* __restrict__ CTX,
                                             const float* __restrict__ H2,
                                             const float* __restrict__ Wout,
                                             const float* __restrict__ bout,
                                             float* __restrict__ out) {
    const int tid = threadIdx.x;
    const int j0 = blockIdx.x * 32;
    const int t = blockIdx.y;
    const int b = tid & 31, jj = tid >> 5;
    __shared__ float xs[32 * 257];
    float acc[4];
#pragma unroll
    for (int r = 0; r < 4; r++) acc[r] = bout[j0 + jj * 4 + r];
    const float* Ct = CTX + (size_t)t * 32 * 1024;
    const float* Ht = H2 + (size_t)t * 32 * 512;
    for (int c = 0; c < 6; c++) {
        for (int idx = tid; idx < 32 * 64; idx += 256) {
            int b2 = idx >> 6, k4 = idx & 63;
            const float* src = (c < 4) ? &Ct[b2 * 1024 + c * 256] : &Ht[b2 * 512 + (c - 4) * 256];
            f4 v = *(const f4*)&src[k4 * 4];
            float* dst = &xs[b2 * 257 + k4 * 4];
            dst[0] = v[0]; dst[1] = v[1]; dst[2] = v[2]; dst[3] = v[3];
        }
        __syncthreads();
        for (int k8 = 0; k8 < 32; k8++) {
            float w[4][8];
#pragma unroll
            for (int r = 0; r < 4; r++) {
                const f4* wp = (const f4*)&Wout[(size_t)(j0 + jj * 4 + r) * 1536 + c * 256 + k8 * 8];
                f4 wa = wp[0], wb = wp[1];
#pragma unroll
                for (int kk = 0; kk < 4; kk++) { w[r][kk] = wa[kk]; w[r][4 + kk] = wb[kk]; }
            }
#pragma unroll
            for (int kk = 0; kk < 8; kk++) {
                float xv = xs[b * 257 + k8 * 8 + kk];
#pragma unroll
                for (int r = 0; r < 4; r++) acc[r] += xv * w[r][kk];
            }
        }
        __syncthreads();
    }
    float* orow = out + ((size_t)(t * 32 + b)) * 512;
#pragma unroll
    for (int r = 0; r < 4; r++) orow[j0 + jj * 4 + r] = tanhf(acc[r]);
}

// ---------------------------------------------------------------------------
extern "C" void kernel_launch(void* const* d_in, const int* in_sizes, int n_in,
                              void* d_out, int out_size, void* d_ws, size_t ws_size,
                              hipStream_t stream) {
    const int* tokens   = (const int*)d_in[0];
    const float* enc    = (const float*)d_in[1];
    const float* hidden = (const float*)d_in[2];
    const float* cells  = (const float*)d_in[3];
    const unsigned char* mask = (const unsigned char*)d_in[4];
    const float* embed  = (const float*)d_in[5];
    const float* W_ih   = (const float*)d_in[6];
    const float* W_hh   = (const float*)d_in[7];
    const float* b_ih   = (const float*)d_in[8];
    const float* b_hh   = (const float*)d_in[9];
    const float* W_in   = (const float*)d_in[10];
    const float* b_in   = (const float*)d_in[11];
    const float* W_out  = (const float*)d_in[12];
    const float* b_out  = (const float*)d_in[13];
    float* out = (float*)d_out;

    float* ws = (float*)d_ws;
    float* gih0 = ws;                              // 4,194,304 f
    float* h0a  = ws + 4194304;                    // 16384
    float* h0b  = ws + 4210688;
    float* h1a  = ws + 4227072;
    float* h1b  = ws + 4243456;
    float* h20  = ws + 4259840;                    // 16384
    float* H2   = ws + 4276224;                    // 1,048,576
    float* XQ   = ws + 5324800;                    // 2,097,152
    float* CTX  = ws + 7421952;                    // 2,097,152
    int*   flag = (int*)(ws + 9519104);

    float* h0buf[2] = { h0a, h0b };
    float* h1buf[2] = { h1a, h1b };

    k_flag<<<1, 256, 0, stream>>>(mask, flag);
    k_init<<<128, 256, 0, stream>>>(hidden, h0a, h1a);
    k_gih0<<<dim3(64, 64), 256, 0, stream>>>(tokens, embed, W_ih, b_ih, b_hh, gih0);

    for (int t = 0; t < TT; t++) {
        k_stepA<<<64, 256, 0, stream>>>(gih0 + (size_t)t * 32 * 2048,
                                        h0buf[t & 1], W_hh, cells,
                                        h0buf[(t + 1) & 1], h20);
        k_stepB<<<64, 256, 0, stream>>>(h20, h1buf[t & 1],
                                        W_ih + (size_t)G4_ * DD, W_hh + (size_t)G4_ * DD,
                                        b_ih + G4_, b_hh + G4_, cells + BB * DD,
                                        h1buf[(t + 1) & 1], H2 + (size_t)t * 32 * 512);
    }

    k_x<<<dim3(32, 64), 256, 0, stream>>>(H2, W_in, b_in, XQ);
    k_att<<<dim3(32, 64), 256, 0, stream>>>(XQ, enc, mask, flag, CTX);
    k_out<<<dim3(16, 64), 256, 0, stream>>>(CTX, H2, W_out, b_out, out);
}